// Round 5
// baseline (99.670 us; speedup 1.0000x reference)
//
#include <hip/hip_runtime.h>

#define GAMMA 0.1f

constexpr int MTOT = 65536;
constexpr int NTOT = 1024;
constexpr int KDIM = 64;
constexpr int BM = 128;
constexpr int BN = 128;

using frag_ab = __attribute__((ext_vector_type(8))) short;  // 8 bf16 (4 VGPRs)
using f32x4   = __attribute__((ext_vector_type(4))) float;  // 4 f32 acc

// f32 -> bf16 round-to-nearest-even; 'back' is the rounded value as f32.
__device__ __forceinline__ ushort bf16_rne(float x, float& back) {
  unsigned u = __float_as_uint(x);
  unsigned r = (u + 0x7FFFu + ((u >> 16) & 1u)) >> 16;
  back = __uint_as_float(r << 16);
  return (ushort)r;
}

// Stage a [128 rows x 64 cols] f32 tile into bf16 hi/lo LDS arrays (XOR-swizzled),
// and write per-row squared norms (from the exact f32 data) into sq[128].
__device__ __forceinline__ void stage_tile(const float* __restrict__ src,
                                           ushort* hi, ushort* lo, float* sq,
                                           int tid) {
  #pragma unroll
  for (int pass = 0; pass < 4; ++pass) {
    const int idx = pass * 2048 + tid * 8;   // flat element index in tile
    const int row = idx >> 6;                // /64
    const int s   = tid & 7;                 // 16B slot within the 128B row
    const float4* p = reinterpret_cast<const float4*>(src + idx);
    float4 v0 = p[0];
    float4 v1 = p[1];
    float v[8] = {v0.x, v0.y, v0.z, v0.w, v1.x, v1.y, v1.z, v1.w};
    frag_ab hv, lv;
    float ss = 0.0f;
    #pragma unroll
    for (int i = 0; i < 8; ++i) {
      float back;
      ushort hb = bf16_rne(v[i], back);
      float b2;
      ushort lb = bf16_rne(v[i] - back, b2);
      (void)b2;
      ss += v[i] * v[i];
      hv[i] = (short)hb;
      lv[i] = (short)lv[i], lv[i] = (short)lb;
    }
    ss += __shfl_xor(ss, 1);
    ss += __shfl_xor(ss, 2);
    ss += __shfl_xor(ss, 4);
    if (s == 0) sq[row] = ss;
    const int slot = s ^ (row & 7);  // bank-conflict XOR swizzle (G4)
    *reinterpret_cast<frag_ab*>(hi + row * 64 + slot * 8) = hv;
    *reinterpret_cast<frag_ab*>(lo + row * 64 + slot * 8) = lv;
  }
}

__global__ __launch_bounds__(256, 2)
void rbf_mfma_kernel(const float* __restrict__ x,
                     const float* __restrict__ centers,
                     float* __restrict__ out) {
  // 64 KB staging region, reused as the f32 out-tile for the store phase.
  __shared__ ushort sStage[4 * 8192];          // 64 KB
  ushort* sAhi = sStage;                       // 128 x 64 bf16-hi (x)
  ushort* sAlo = sStage + 8192;
  ushort* sBhi = sStage + 16384;               // 128 x 64 bf16-hi (centers)
  ushort* sBlo = sStage + 24576;
  float*  sOut = reinterpret_cast<float*>(sStage);  // union: 128 x 128 f32
  __shared__ float sAsq[BM];
  __shared__ float sBsq[BN];

  const int tid = threadIdx.x;
  // XCD-aware mapping: hardware XCD = blockIdx.x % 8. Keep all 8 nt-blocks of
  // one mt on the SAME XCD and consecutive in dispatch, so the x-tile is
  // fetched into that XCD's L2 once and reused 8x; centers (262 KB) stays
  // L2-resident per XCD across all its mts.
  const int xcd = blockIdx.x & 7;
  const int s_  = blockIdx.x >> 3;       // 0..511 within-XCD sequence
  const int nt  = s_ & 7;                // 8 n-tiles
  const int mt  = (s_ >> 3) * 8 + xcd;   // 512 m-tiles, striped across XCDs

  stage_tile(x       + (size_t)mt * BM * KDIM, sAhi, sAlo, sAsq, tid);
  stage_tile(centers + (size_t)nt * BN * KDIM, sBhi, sBlo, sBsq, tid);
  __syncthreads();

  const int lane = tid & 63;
  const int wave = tid >> 6;
  const int wr = wave >> 1;        // wave row 0..1   (64 x-rows each)
  const int wc = wave & 1;         // wave col 0..1   (64 centers each)
  const int r16 = lane & 15;
  const int g   = lane >> 4;       // 0..3 k-group

  f32x4 acc[4][4] = {};

  #pragma unroll
  for (int ks = 0; ks < 2; ++ks) {
    const int slot = (ks * 4 + g) ^ (r16 & 7);   // matches staging swizzle
    frag_ab ah[4], al[4], bh[4], bl[4];
    #pragma unroll
    for (int m = 0; m < 4; ++m) {
      const int row = wr * 64 + m * 16 + r16;
      ah[m] = *reinterpret_cast<const frag_ab*>(sAhi + row * 64 + slot * 8);
      al[m] = *reinterpret_cast<const frag_ab*>(sAlo + row * 64 + slot * 8);
    }
    #pragma unroll
    for (int n = 0; n < 4; ++n) {
      const int row = wc * 64 + n * 16 + r16;
      bh[n] = *reinterpret_cast<const frag_ab*>(sBhi + row * 64 + slot * 8);
      bl[n] = *reinterpret_cast<const frag_ab*>(sBlo + row * 64 + slot * 8);
    }
    #pragma unroll
    for (int m = 0; m < 4; ++m) {
      #pragma unroll
      for (int n = 0; n < 4; ++n) {
        // cross = xh*ch + xh*cl + xl*ch  (lo*lo dropped, ~1e-6 rel)
        acc[m][n] = __builtin_amdgcn_mfma_f32_16x16x32_bf16(ah[m], bh[n], acc[m][n], 0, 0, 0);
        acc[m][n] = __builtin_amdgcn_mfma_f32_16x16x32_bf16(ah[m], bl[n], acc[m][n], 0, 0, 0);
        acc[m][n] = __builtin_amdgcn_mfma_f32_16x16x32_bf16(al[m], bh[n], acc[m][n], 0, 0, 0);
      }
    }
  }

  // Norms into registers BEFORE the staging LDS is overwritten.
  float4 xs4[4];
  #pragma unroll
  for (int m = 0; m < 4; ++m)
    xs4[m] = *reinterpret_cast<const float4*>(&sAsq[wr * 64 + m * 16 + g * 4]);
  float csq_[4];
  #pragma unroll
  for (int n = 0; n < 4; ++n) csq_[n] = sBsq[wc * 64 + n * 16 + r16];

  __syncthreads();   // all frag reads done -> safe to overwrite staging with out-tile

  // ---- epilogue: exp(-g*max(xsq+csq-2*cross,0)) -> LDS out-tile (swizzled) ----
  // sOut[row][col] at row*128 + ((col>>2)^(((row>>2)&7)<<2))*4 + (col&3).
  // Write conflicts: bank = r16 + 16*((n^g)&1) -> 2-way (free).
  #pragma unroll
  for (int m = 0; m < 4; ++m) {
    #pragma unroll
    for (int r = 0; r < 4; ++r) {
      const int row = wr * 64 + m * 16 + g * 4 + r;
      const float xs = ((const float*)&xs4[m])[r];
      const int swz = ((row >> 2) & 7) << 2;
      float* orow = sOut + row * 128;
      #pragma unroll
      for (int n = 0; n < 4; ++n) {
        const int col = wc * 64 + n * 16 + r16;
        const float l2 = fmaxf(xs + csq_[n] - 2.0f * acc[m][n][r], 0.0f);
        const int cc = (col >> 2) ^ swz;
        orow[cc * 4 + (col & 3)] = __expf(-GAMMA * l2);
      }
    }
  }
  __syncthreads();

  // ---- streamed store: per inst each wave covers 2 rows x 512B contiguous ----
  const size_t row0 = (size_t)mt * BM;
  const int col0 = nt * BN;
  #pragma unroll
  for (int p = 0; p < 16; ++p) {
    const int q = p * 256 + tid;        // 16B chunk id: 128 rows x 32 chunks
    const int row = q >> 5;
    const int cc = q & 31;
    const int ccs = cc ^ (((row >> 2) & 7) << 2);
    const f32x4 v = *reinterpret_cast<const f32x4*>(sOut + row * 128 + ccs * 4);
    *reinterpret_cast<f32x4*>(out + (row0 + row) * (size_t)NTOT + col0 + cc * 4) = v;
  }
}

extern "C" void kernel_launch(void* const* d_in, const int* in_sizes, int n_in,
                              void* d_out, int out_size, void* d_ws, size_t ws_size,
                              hipStream_t stream) {
  (void)in_sizes; (void)n_in; (void)d_ws; (void)ws_size; (void)out_size;
  const float* x       = (const float*)d_in[0];
  const float* centers = (const float*)d_in[1];
  float* out = (float*)d_out;
  const int grid = (MTOT / BM) * (NTOT / BN);   // 512 * 8 = 4096
  rbf_mfma_kernel<<<grid, 256, 0, stream>>>(x, centers, out);
}

// Round 6
// 80.327 us; speedup vs baseline: 1.2408x; 1.2408x over previous
//
#include <hip/hip_runtime.h>

#define GAMMA 0.1f

constexpr int MTOT = 65536;
constexpr int NTOT = 1024;
constexpr int KDIM = 64;
constexpr int BM = 128;
constexpr int BN = 128;

using frag_ab = __attribute__((ext_vector_type(8))) short;  // 8 bf16 (4 VGPRs)
using f32x4   = __attribute__((ext_vector_type(4))) float;  // 4 f32 acc

// f32 -> bf16 round-to-nearest-even; 'back' is the rounded value as f32.
__device__ __forceinline__ ushort bf16_rne(float x, float& back) {
  unsigned u = __float_as_uint(x);
  unsigned r = (u + 0x7FFFu + ((u >> 16) & 1u)) >> 16;
  back = __uint_as_float(r << 16);
  return (ushort)r;
}

// Stage a [128 rows x 64 cols] f32 tile into bf16 hi/lo LDS arrays (XOR-swizzled),
// and write per-row squared norms (from the exact f32 data) into sq[128].
// 256 threads, 8 consecutive f32 per thread per pass, 4 passes.
__device__ __forceinline__ void stage_tile(const float* __restrict__ src,
                                           ushort* hi, ushort* lo, float* sq,
                                           int tid) {
  #pragma unroll
  for (int pass = 0; pass < 4; ++pass) {
    const int idx = pass * 2048 + tid * 8;   // flat element index in tile
    const int row = idx >> 6;                // /64
    const int s   = tid & 7;                 // 16B slot within the 128B row
    const float4* p = reinterpret_cast<const float4*>(src + idx);
    float4 v0 = p[0];
    float4 v1 = p[1];
    float v[8] = {v0.x, v0.y, v0.z, v0.w, v1.x, v1.y, v1.z, v1.w};
    frag_ab hv, lv;
    float ss = 0.0f;
    #pragma unroll
    for (int i = 0; i < 8; ++i) {
      float back;
      ushort hb = bf16_rne(v[i], back);
      float back2;
      ushort lb = bf16_rne(v[i] - back, back2);
      (void)back2;
      ss += v[i] * v[i];
      hv[i] = (short)hb;
      lv[i] = (short)lb;
    }
    // 8 lanes share a row
    ss += __shfl_xor(ss, 1);
    ss += __shfl_xor(ss, 2);
    ss += __shfl_xor(ss, 4);
    if (s == 0) sq[row] = ss;
    const int slot = s ^ (row & 7);  // bank-conflict XOR swizzle (G4)
    *reinterpret_cast<frag_ab*>(hi + row * 64 + slot * 8) = hv;
    *reinterpret_cast<frag_ab*>(lo + row * 64 + slot * 8) = lv;
  }
}

__global__ __launch_bounds__(256, 2)
void rbf_mfma_kernel(const float* __restrict__ x,
                     const float* __restrict__ centers,
                     float* __restrict__ out) {
  __shared__ ushort sAhi[BM * 64];
  __shared__ ushort sAlo[BM * 64];
  __shared__ ushort sBhi[BN * 64];
  __shared__ ushort sBlo[BN * 64];
  __shared__ float  sAsq[BM];
  __shared__ float  sBsq[BN];

  const int tid = threadIdx.x;
  const int mt = blockIdx.x >> 3;   // 512 m-tiles (R1 mapping: known-good)
  const int nt = blockIdx.x & 7;    // 8 n-tiles

  stage_tile(x       + (size_t)mt * BM * KDIM, sAhi, sAlo, sAsq, tid);
  stage_tile(centers + (size_t)nt * BN * KDIM, sBhi, sBlo, sBsq, tid);
  __syncthreads();

  const int lane = tid & 63;
  const int wave = tid >> 6;
  const int wr = wave >> 1;        // wave row 0..1   (64 rows each)
  const int wc = wave & 1;         // wave col 0..1   (64 cols each)
  const int r16 = lane & 15;
  const int g   = lane >> 4;       // 0..3 k-group

  f32x4 acc[4][4] = {};

  #pragma unroll
  for (int ks = 0; ks < 2; ++ks) {
    const int slot = (ks * 4 + g) ^ (r16 & 7);   // matches staging swizzle
    frag_ab ah[4], al[4], bh[4], bl[4];
    #pragma unroll
    for (int m = 0; m < 4; ++m) {
      const int row = wr * 64 + m * 16 + r16;
      ah[m] = *reinterpret_cast<const frag_ab*>(sAhi + row * 64 + slot * 8);
      al[m] = *reinterpret_cast<const frag_ab*>(sAlo + row * 64 + slot * 8);
    }
    #pragma unroll
    for (int n = 0; n < 4; ++n) {
      const int row = wc * 64 + n * 16 + r16;
      bh[n] = *reinterpret_cast<const frag_ab*>(sBhi + row * 64 + slot * 8);
      bl[n] = *reinterpret_cast<const frag_ab*>(sBlo + row * 64 + slot * 8);
    }
    #pragma unroll
    for (int m = 0; m < 4; ++m) {
      #pragma unroll
      for (int n = 0; n < 4; ++n) {
        // cross = xh*ch + xh*cl + xl*ch  (lo*lo dropped, ~1e-6 rel)
        acc[m][n] = __builtin_amdgcn_mfma_f32_16x16x32_bf16(ah[m], bh[n], acc[m][n], 0, 0, 0);
        acc[m][n] = __builtin_amdgcn_mfma_f32_16x16x32_bf16(ah[m], bl[n], acc[m][n], 0, 0, 0);
        acc[m][n] = __builtin_amdgcn_mfma_f32_16x16x32_bf16(al[m], bh[n], acc[m][n], 0, 0, 0);
      }
    }
  }

  // Epilogue: out = exp(-g * max(xsq + csq - 2*cross, 0))
  // NONTEMPORAL stores: keep the 268 MB write stream out of L2/L3 so the
  // x/centers working set stays cache-resident (write-thrash theory, R6).
  float csq[4];
  #pragma unroll
  for (int n = 0; n < 4; ++n) csq[n] = sBsq[wc * 64 + n * 16 + r16];

  const size_t row0 = (size_t)mt * BM;
  const int col0 = nt * BN + wc * 64;

  #pragma unroll
  for (int m = 0; m < 4; ++m) {
    #pragma unroll
    for (int r = 0; r < 4; ++r) {
      const int rl = wr * 64 + m * 16 + g * 4 + r;   // local out row
      const float xs = sAsq[rl];
      float* orow = out + (row0 + rl) * (size_t)NTOT + col0;
      #pragma unroll
      for (int n = 0; n < 4; ++n) {
        float l2 = fmaxf(xs + csq[n] - 2.0f * acc[m][n][r], 0.0f);
        __builtin_nontemporal_store(__expf(-GAMMA * l2), &orow[n * 16 + r16]);
      }
    }
  }
}

extern "C" void kernel_launch(void* const* d_in, const int* in_sizes, int n_in,
                              void* d_out, int out_size, void* d_ws, size_t ws_size,
                              hipStream_t stream) {
  (void)in_sizes; (void)n_in; (void)d_ws; (void)ws_size; (void)out_size;
  const float* x       = (const float*)d_in[0];
  const float* centers = (const float*)d_in[1];
  float* out = (float*)d_out;
  const int grid = (MTOT / BM) * (NTOT / BN);   // 512 * 8 = 4096
  rbf_mfma_kernel<<<grid, 256, 0, stream>>>(x, centers, out);
}

// Round 7
// 71.631 us; speedup vs baseline: 1.3914x; 1.1214x over previous
//
#include <hip/hip_runtime.h>

#define GAMMA 0.1f

constexpr int MTOT = 65536;
constexpr int NTOT = 1024;
constexpr int KDIM = 64;
constexpr int BM = 64;        // x rows per m-tile
constexpr int BN = 128;       // centers per block
constexpr int NTIL = 16;      // m-tiles per block
// grid = 8 nt * 64 mg = 512 blocks = exactly 2 resident blocks per CU (persistent)

using frag_ab = __attribute__((ext_vector_type(8))) short;  // 8 bf16 (4 VGPRs)
using f32x4   = __attribute__((ext_vector_type(4))) float;  // 4 f32 acc

typedef __attribute__((address_space(1))) const unsigned int gu32;
typedef __attribute__((address_space(3))) unsigned int lu32;

// f32 -> bf16 round-to-nearest-even; 'back' is the rounded value as f32.
__device__ __forceinline__ ushort bf16_rne(float x, float& back) {
  unsigned u = __float_as_uint(x);
  unsigned r = (u + 0x7FFFu + ((u >> 16) & 1u)) >> 16;
  back = __uint_as_float(r << 16);
  return (ushort)r;
}

__global__ __launch_bounds__(512, 4)
void rbf_persistent_kernel(const float* __restrict__ x,
                           const float* __restrict__ centers,
                           float* __restrict__ out) {
  __shared__ ushort sChi[BN * KDIM];                 // 16 KB (XOR-swizzled, R1 scheme)
  __shared__ ushort sClo[BN * KDIM];                 // 16 KB
  __shared__ float  sCsq[BN];                        // 512 B
  __shared__ __align__(16) float sX[2][BM * KDIM];   // 2 x 16 KB f32 dbuf (DMA dest)

  const int tid = threadIdx.x;
  const int nt = blockIdx.x & 7;    // R1 known-good mapping
  const int mg = blockIdx.x >> 3;   // 0..63; block handles mt = mg + 64*j

  // ---- DMA issue: x m-tile (16 KB contiguous) -> sX[b], source pre-swizzled ----
  // LDS dest is linear (wave-uniform base + lane*16, as HW requires); the global
  // source chunk is XOR-permuted so that fragment reads (slot = chunk ^ (row&15))
  // land conflict-free. Involution: slot s holds global chunk s ^ (row&15).
  auto issue_x = [&](int mt, int b) {
    const char* src = reinterpret_cast<const char*>(x) + (size_t)mt * BM * KDIM * 4;
    char* dst = reinterpret_cast<char*>(&sX[b][0]);
    #pragma unroll
    for (int p = 0; p < 2; ++p) {
      const int q = p * 512 + tid;          // 16B chunk id 0..1023
      const int row = q >> 4;
      const int s = q & 15;
      const int sc = (row << 4) | (s ^ (row & 15));
      __builtin_amdgcn_global_load_lds((gu32*)(src + (size_t)sc * 16),
                                       (lu32*)(dst + (size_t)q * 16), 16, 0, 0);
    }
  };

  issue_x(mg, 0);   // prefetch tile 0 (overlaps centers staging below)

  // ---- stage centers tile once: f32 -> bf16 hi/lo (XOR-swizzled) + csq ----
  #pragma unroll
  for (int pass = 0; pass < 2; ++pass) {
    const int idx = pass * 4096 + tid * 8;
    const int row = idx >> 6;               // 0..127
    const int s = tid & 7;
    const float4* p = reinterpret_cast<const float4*>(
        centers + (size_t)nt * BN * KDIM + idx);
    float4 v0 = p[0], v1 = p[1];
    float v[8] = {v0.x, v0.y, v0.z, v0.w, v1.x, v1.y, v1.z, v1.w};
    frag_ab hv, lv;
    float ss = 0.0f;
    #pragma unroll
    for (int i = 0; i < 8; ++i) {
      float back;
      ushort hb = bf16_rne(v[i], back);
      float b2;
      ushort lb = bf16_rne(v[i] - back, b2);
      (void)b2;
      ss += v[i] * v[i];
      hv[i] = (short)hb;
      lv[i] = (short)lb;
    }
    ss += __shfl_xor(ss, 1);
    ss += __shfl_xor(ss, 2);
    ss += __shfl_xor(ss, 4);
    if (s == 0) sCsq[row] = ss;
    const int slot = s ^ (row & 7);
    *reinterpret_cast<frag_ab*>(sChi + row * 64 + slot * 8) = hv;
    *reinterpret_cast<frag_ab*>(sClo + row * 64 + slot * 8) = lv;
  }
  __syncthreads();   // centers staged AND x-tile 0 DMA drained (vmcnt in barrier)

  const int lane = tid & 63;
  const int wave = tid >> 6;        // 0..7
  const int wm = wave & 3;          // m-quarter: 16 x-rows
  const int wn = wave >> 2;         // n-half: 64 centers
  const int l = lane & 15;
  const int g = lane >> 4;          // k-group 0..3

  // ---- hoist centers-hi fragments (invariant across m-tiles) + csq ----
  float csq_[4];
  #pragma unroll
  for (int nf = 0; nf < 4; ++nf) csq_[nf] = sCsq[wn * 64 + nf * 16 + l];
  frag_ab ch[4][2];
  #pragma unroll
  for (int nf = 0; nf < 4; ++nf) {
    #pragma unroll
    for (int ks = 0; ks < 2; ++ks) {
      const int row = wn * 64 + nf * 16 + l;
      const int slot = (ks * 4 + g) ^ (l & 7);
      ch[nf][ks] = *reinterpret_cast<const frag_ab*>(sChi + row * 64 + slot * 8);
    }
  }

  // ================= persistent m-loop: 16 tiles, 1 barrier each =================
  #pragma unroll 1
  for (int j = 0; j < NTIL; ++j) {
    const int mt = mg + 64 * j;     // interleaved: GPU-wide writes stay dense
    const int b = j & 1;

    // ---- x fragments from LDS f32 (swizzled slots -> conflict-free b128) ----
    float ss = 0.0f;
    frag_ab xh[2], xl[2];
    #pragma unroll
    for (int ks = 0; ks < 2; ++ks) {
      const int cb = ks * 8 + g * 2;
      const float* base = &sX[b][(wm * 16 + l) * KDIM];
      const float4 a0 = *reinterpret_cast<const float4*>(base + ((cb) ^ l) * 4);
      const float4 a1 = *reinterpret_cast<const float4*>(base + ((cb + 1) ^ l) * 4);
      float v[8] = {a0.x, a0.y, a0.z, a0.w, a1.x, a1.y, a1.z, a1.w};
      frag_ab h, lo_;
      #pragma unroll
      for (int i = 0; i < 8; ++i) {
        float back;
        ushort hb = bf16_rne(v[i], back);
        float b2;
        ushort lb = bf16_rne(v[i] - back, b2);
        (void)b2;
        ss += v[i] * v[i];
        h[i] = (short)hb;
        lo_[i] = (short)lb;
      }
      xh[ks] = h;
      xl[ks] = lo_;
    }
    // full row-sum: reduce across the 4 k-groups
    ss += __shfl_xor(ss, 16);
    ss += __shfl_xor(ss, 32);

    // ---- prefetch next x-tile into the other buffer (hidden under MFMA+epilogue) ----
    if (j + 1 < NTIL) issue_x(mg + 64 * (j + 1), b ^ 1);

    // ---- MFMA: cross = xh*ch + xh*cl + xl*ch (lo*lo dropped, ~1e-6) ----
    f32x4 acc[4] = {};
    #pragma unroll
    for (int ks = 0; ks < 2; ++ks) {
      #pragma unroll
      for (int nf = 0; nf < 4; ++nf) {
        const int row = wn * 64 + nf * 16 + l;
        const int slot = (ks * 4 + g) ^ (l & 7);
        const frag_ab cl = *reinterpret_cast<const frag_ab*>(sClo + row * 64 + slot * 8);
        acc[nf] = __builtin_amdgcn_mfma_f32_16x16x32_bf16(xh[ks], ch[nf][ks], acc[nf], 0, 0, 0);
        acc[nf] = __builtin_amdgcn_mfma_f32_16x16x32_bf16(xl[ks], ch[nf][ks], acc[nf], 0, 0, 0);
        acc[nf] = __builtin_amdgcn_mfma_f32_16x16x32_bf16(xh[ks], cl, acc[nf], 0, 0, 0);
      }
    }

    // ---- epilogue: finish per-col, cross-lane repack to float2 -> FULL-LINE stores ----
    // acc[nf][r]: row = g*4+r (x-row), col = nf*16+l (center). After repack, the
    // 16 lanes of each g-group write cols [p*32 .. p*32+31] = one 128B line/inst.
    #pragma unroll
    for (int r = 0; r < 4; ++r) {
      const int rloc = g * 4 + r;
      const float xs = __shfl(ss, (lane & 48) | rloc);       // row sum for this out-row
      const size_t rowg = (size_t)mt * BM + wm * 16 + rloc;
      float ov[4];
      #pragma unroll
      for (int nf = 0; nf < 4; ++nf)
        ov[nf] = __expf(-GAMMA * fmaxf(xs + csq_[nf] - 2.0f * acc[nf][r], 0.0f));
      #pragma unroll
      for (int p = 0; p < 2; ++p) {
        const int s1 = (lane & 48) | ((2 * l) & 15);
        const int s2 = (lane & 48) | ((2 * l + 1) & 15);
        const float a1 = __shfl(ov[2 * p], s1),     b1 = __shfl(ov[2 * p + 1], s1);
        const float a2 = __shfl(ov[2 * p], s2),     b2 = __shfl(ov[2 * p + 1], s2);
        float2 o;
        o.x = (l < 8) ? a1 : b1;    // col p*32 + 2l
        o.y = (l < 8) ? a2 : b2;    // col p*32 + 2l + 1
        *reinterpret_cast<float2*>(
            out + rowg * (size_t)NTOT + nt * BN + wn * 64 + p * 32 + 2 * l) = o;
      }
    }

    __syncthreads();   // next-tile DMA drained; buffer b free for tile j+2
  }
}

extern "C" void kernel_launch(void* const* d_in, const int* in_sizes, int n_in,
                              void* d_out, int out_size, void* d_ws, size_t ws_size,
                              hipStream_t stream) {
  (void)in_sizes; (void)n_in; (void)d_ws; (void)ws_size; (void)out_size;
  const float* x       = (const float*)d_in[0];
  const float* centers = (const float*)d_in[1];
  float* out = (float*)d_out;
  rbf_persistent_kernel<<<512, 512, 0, stream>>>(x, centers, out);
}

// Round 8
// 69.042 us; speedup vs baseline: 1.4436x; 1.0375x over previous
//
#include <hip/hip_runtime.h>

#define GAMMA 0.1f

constexpr int MTOT = 65536;
constexpr int NTOT = 1024;
constexpr int KDIM = 64;
constexpr int BM = 64;        // x rows per m-tile
constexpr int BN = 128;       // centers per block
constexpr int NTIL = 16;      // m-tiles per block
// grid = 8 nt * 64 mg = 512 blocks = exactly 2 resident blocks per CU (persistent)

using frag_ab = __attribute__((ext_vector_type(8))) short;  // 8 bf16 (4 VGPRs)
using f32x4   = __attribute__((ext_vector_type(4))) float;  // 4 f32 acc

typedef __attribute__((address_space(1))) const unsigned int gu32;
typedef __attribute__((address_space(3))) unsigned int lu32;

// f32 -> bf16 round-to-nearest-even; 'back' is the rounded value as f32.
__device__ __forceinline__ ushort bf16_rne(float x, float& back) {
  unsigned u = __float_as_uint(x);
  unsigned r = (u + 0x7FFFu + ((u >> 16) & 1u)) >> 16;
  back = __uint_as_float(r << 16);
  return (ushort)r;
}

__global__ __launch_bounds__(512, 4)
void rbf_persistent_kernel(const float* __restrict__ x,
                           const float* __restrict__ centers,
                           float* __restrict__ out) {
  __shared__ ushort sChi[BN * KDIM];                 // 16 KB (XOR-swizzled)
  __shared__ ushort sClo[BN * KDIM];                 // 16 KB
  __shared__ float  sCsq[BN];                        // 512 B
  __shared__ __align__(16) float sX[2][BM * KDIM];   // 2 x 16 KB f32 dbuf (DMA dest)

  const int tid = threadIdx.x;
  const int nt = blockIdx.x & 7;
  const int mg = blockIdx.x >> 3;   // 0..63; block handles mt = mg + 64*j

  // ---- DMA issue: x m-tile (16 KB contiguous) -> sX[b], source pre-swizzled ----
  // LDS dest linear (HW requirement); global source chunk XOR-permuted so the
  // fragment reads (slot = chunk ^ (row&15)) are conflict-free (m173 pattern).
  auto issue_x = [&](int mt, int b) {
    const char* src = reinterpret_cast<const char*>(x) + (size_t)mt * BM * KDIM * 4;
    char* dst = reinterpret_cast<char*>(&sX[b][0]);
    #pragma unroll
    for (int p = 0; p < 2; ++p) {
      const int q = p * 512 + tid;          // 16B chunk id 0..1023
      const int row = q >> 4;
      const int s = q & 15;
      const int sc = (row << 4) | (s ^ (row & 15));
      __builtin_amdgcn_global_load_lds((gu32*)(src + (size_t)sc * 16),
                                       (lu32*)(dst + (size_t)q * 16), 16, 0, 0);
    }
  };

  issue_x(mg, 0);   // prefetch tile 0 (overlaps centers staging below)

  // ---- stage centers tile once: f32 -> bf16 hi/lo (XOR-swizzled) + csq ----
  #pragma unroll
  for (int pass = 0; pass < 2; ++pass) {
    const int idx = pass * 4096 + tid * 8;
    const int row = idx >> 6;               // 0..127
    const int s = tid & 7;
    const float4* p = reinterpret_cast<const float4*>(
        centers + (size_t)nt * BN * KDIM + idx);
    float4 v0 = p[0], v1 = p[1];
    float v[8] = {v0.x, v0.y, v0.z, v0.w, v1.x, v1.y, v1.z, v1.w};
    frag_ab hv, lv;
    float ss = 0.0f;
    #pragma unroll
    for (int i = 0; i < 8; ++i) {
      float back;
      ushort hb = bf16_rne(v[i], back);
      float b2;
      ushort lb = bf16_rne(v[i] - back, b2);
      (void)b2;
      ss += v[i] * v[i];
      hv[i] = (short)hb;
      lv[i] = (short)lb;
    }
    ss += __shfl_xor(ss, 1);
    ss += __shfl_xor(ss, 2);
    ss += __shfl_xor(ss, 4);
    if (s == 0) sCsq[row] = ss;
    const int slot = s ^ (row & 7);
    *reinterpret_cast<frag_ab*>(sChi + row * 64 + slot * 8) = hv;
    *reinterpret_cast<frag_ab*>(sClo + row * 64 + slot * 8) = lv;
  }
  __syncthreads();   // centers staged AND x-tile 0 DMA drained

  const int lane = tid & 63;
  const int wave = tid >> 6;        // 0..7
  const int wm = wave & 3;          // m-quarter: 16 x-rows
  const int wn = wave >> 2;         // n-half: 64 centers
  const int l = lane & 15;
  const int g = lane >> 4;          // k-group 0..3

  // ---- hoist centers-hi fragments + csq float4s (invariant across m-tiles) ----
  // A-operand = centers: lane l <-> center row (wn*64 + nf*16 + l), k-chunk g.
  frag_ab ch[4][2];
  #pragma unroll
  for (int nf = 0; nf < 4; ++nf) {
    #pragma unroll
    for (int ks = 0; ks < 2; ++ks) {
      const int row = wn * 64 + nf * 16 + l;
      const int slot = (ks * 4 + g) ^ (l & 7);
      ch[nf][ks] = *reinterpret_cast<const frag_ab*>(sChi + row * 64 + slot * 8);
    }
  }
  // D-layout (A=centers, B=x): col=lane&15 -> x-row l; row=g*4+reg -> center.
  // Lane (g,l) owns centers nf*16 + g*4 + {0..3} at x-row l -> float4 epilogue.
  float4 csq4[4];
  #pragma unroll
  for (int nf = 0; nf < 4; ++nf)
    csq4[nf] = *reinterpret_cast<const float4*>(&sCsq[wn * 64 + nf * 16 + g * 4]);

  const int ncol0 = nt * BN + wn * 64;

  // ================= persistent m-loop: 16 tiles, 1 barrier each =================
  #pragma unroll 1
  for (int j = 0; j < NTIL; ++j) {
    const int mt = mg + 64 * j;     // interleaved: GPU-wide writes stay dense
    const int b = j & 1;

    // ---- x fragments from LDS f32 (swizzled slots -> conflict-free b128) ----
    // B-operand = x: lane l <-> x-row (wm*16 + l), k-chunk g. Identical frag
    // indexing to R7 (verified); only the mfma argument order changes.
    float ss = 0.0f;
    frag_ab xh[2], xl[2];
    #pragma unroll
    for (int ks = 0; ks < 2; ++ks) {
      const int cb = ks * 8 + g * 2;
      const float* base = &sX[b][(wm * 16 + l) * KDIM];
      const float4 a0 = *reinterpret_cast<const float4*>(base + ((cb) ^ l) * 4);
      const float4 a1 = *reinterpret_cast<const float4*>(base + ((cb + 1) ^ l) * 4);
      float v[8] = {a0.x, a0.y, a0.z, a0.w, a1.x, a1.y, a1.z, a1.w};
      frag_ab h, lo_;
      #pragma unroll
      for (int i = 0; i < 8; ++i) {
        float back;
        ushort hb = bf16_rne(v[i], back);
        float b2;
        ushort lb = bf16_rne(v[i] - back, b2);
        (void)b2;
        ss += v[i] * v[i];
        h[i] = (short)hb;
        lo_[i] = (short)lb;
      }
      xh[ks] = h;
      xl[ks] = lo_;
    }
    // full row-sum for x-row (wm*16+l): reduce across the 4 k-groups.
    // After this, lane (g,l) holds xs for row l == its OWN output row. No bcast.
    ss += __shfl_xor(ss, 16);
    ss += __shfl_xor(ss, 32);

    // ---- prefetch next x-tile (hidden under MFMA+epilogue) ----
    if (j + 1 < NTIL) issue_x(mg + 64 * (j + 1), b ^ 1);

    // ---- MFMA: cross = ch*xh + ch*xl + cl*xh (lo*lo dropped, ~1e-6) ----
    f32x4 acc[4] = {};
    #pragma unroll
    for (int ks = 0; ks < 2; ++ks) {
      #pragma unroll
      for (int nf = 0; nf < 4; ++nf) {
        const int row = wn * 64 + nf * 16 + l;
        const int slot = (ks * 4 + g) ^ (l & 7);
        const frag_ab cl = *reinterpret_cast<const frag_ab*>(sClo + row * 64 + slot * 8);
        acc[nf] = __builtin_amdgcn_mfma_f32_16x16x32_bf16(ch[nf][ks], xh[ks], acc[nf], 0, 0, 0);
        acc[nf] = __builtin_amdgcn_mfma_f32_16x16x32_bf16(ch[nf][ks], xl[ks], acc[nf], 0, 0, 0);
        acc[nf] = __builtin_amdgcn_mfma_f32_16x16x32_bf16(cl, xh[ks], acc[nf], 0, 0, 0);
      }
    }

    // ---- epilogue: lane-local finish, float4 stores along n (no shuffles) ----
    const size_t rowg = (size_t)mt * BM + wm * 16 + l;
    float* orow = out + rowg * (size_t)NTOT + ncol0;
    #pragma unroll
    for (int nf = 0; nf < 4; ++nf) {
      const f32x4 a = acc[nf];
      const float4 cs = csq4[nf];
      float4 o;
      o.x = __expf(-GAMMA * fmaxf(ss + cs.x - 2.0f * a[0], 0.0f));
      o.y = __expf(-GAMMA * fmaxf(ss + cs.y - 2.0f * a[1], 0.0f));
      o.z = __expf(-GAMMA * fmaxf(ss + cs.z - 2.0f * a[2], 0.0f));
      o.w = __expf(-GAMMA * fmaxf(ss + cs.w - 2.0f * a[3], 0.0f));
      *reinterpret_cast<float4*>(orow + nf * 16 + g * 4) = o;
    }

    __syncthreads();   // next-tile DMA drained; buffer b free for tile j+2
  }
}

extern "C" void kernel_launch(void* const* d_in, const int* in_sizes, int n_in,
                              void* d_out, int out_size, void* d_ws, size_t ws_size,
                              hipStream_t stream) {
  (void)in_sizes; (void)n_in; (void)d_ws; (void)ws_size; (void)out_size;
  const float* x       = (const float*)d_in[0];
  const float* centers = (const float*)d_in[1];
  float* out = (float*)d_out;
  rbf_persistent_kernel<<<512, 512, 0, stream>>>(x, centers, out);
}